// Round 1
// 695.033 us; speedup vs baseline: 1.0990x; 1.0990x over previous
//
#include <hip/hip_runtime.h>
#include <hip/hip_fp16.h>

#define EMB 64
#define BROWS 128
#define BSHIFT 7
#define LDSN 2048          // max buckets supported (2048*128 = 262144 rows)
#define CHUNK 16384        // edges per scatter block
#define SORT_CAP 5120      // per-bucket LDS staging capacity (mean 2560, sigma ~51)

// ---- bucket histogram (LDS-privatized) ----
__global__ __launch_bounds__(256) void bucket_hist(const int* __restrict__ rows,
                                                   int* __restrict__ counts,
                                                   int nnz, int nbuck) {
    __shared__ int lc[LDSN];
    for (int i = threadIdx.x; i < LDSN; i += 256) lc[i] = 0;
    __syncthreads();
    int stride = gridDim.x * blockDim.x;
    for (int i = blockIdx.x * blockDim.x + threadIdx.x; i < nnz; i += stride)
        atomicAdd(&lc[rows[i] >> BSHIFT], 1);
    __syncthreads();
    for (int i = threadIdx.x; i < nbuck; i += 256) {
        int v = lc[i];
        if (v) atomicAdd(&counts[i], v);
    }
}

// ---- exclusive scan of bucket counts (single block) ----
__global__ void scan_buckets(const int* __restrict__ counts, int* __restrict__ bstart,
                             int* __restrict__ cursor, int nbuck) {
    __shared__ int lds[256];
    int tid = threadIdx.x;
    int run = 0;
    for (int base = 0; base < nbuck; base += 256) {
        int idx = base + tid;
        int v = (idx < nbuck) ? counts[idx] : 0;
        int x = v;
        lds[tid] = x; __syncthreads();
        for (int off = 1; off < 256; off <<= 1) {
            int t = (tid >= off) ? lds[tid - off] : 0;
            __syncthreads();
            x += t; lds[tid] = x; __syncthreads();
        }
        if (idx < nbuck) { int ex = run + x - v; bstart[idx] = ex; cursor[idx] = ex; }
        int tot = lds[255];
        __syncthreads();
        run += tot;
    }
    if (tid == 0) bstart[nbuck] = run;
}

// ---- bucket scatter: per-block run reservation (1 atomic per bucket per block) ----
// packed word0 = col | (row_local << 18)   (col < 2^18, row_local < 128)
__global__ __launch_bounds__(256) void bucket_scatter(
        const int* __restrict__ rows, const int* __restrict__ cols,
        const float* __restrict__ vals, int* __restrict__ cursor,
        int2* __restrict__ packed, int nnz) {
    __shared__ int lc[LDSN];
    __shared__ int lbase[LDSN];
    int base = blockIdx.x * CHUNK;
    int end = min(base + CHUNK, nnz);
    for (int i = threadIdx.x; i < LDSN; i += 256) lc[i] = 0;
    __syncthreads();
    for (int i = base + threadIdx.x; i < end; i += 256)
        atomicAdd(&lc[rows[i] >> BSHIFT], 1);
    __syncthreads();
    for (int i = threadIdx.x; i < LDSN; i += 256) {
        int v = lc[i];
        lbase[i] = v ? atomicAdd(&cursor[i], v) : 0;
        lc[i] = 0;   // reuse as local fill cursor
    }
    __syncthreads();
    for (int i = base + threadIdx.x; i < end; i += 256) {
        int r = rows[i];
        int bk = r >> BSHIFT;
        int slot = lbase[bk] + atomicAdd(&lc[bk], 1);
        packed[slot] = make_int2(cols[i] | ((r & (BROWS - 1)) << 18),
                                 __float_as_int(vals[i]));
    }
}

// ---- per-bucket in-place counting sort by row_local; emits exact CSR offs ----
__global__ __launch_bounds__(256) void sort_bucket(
        int2* __restrict__ packed, const int* __restrict__ bstart,
        int* __restrict__ offs, int n_rows, int nbuck) {
    __shared__ int2 ebuf[SORT_CAP];     // 40 KB
    __shared__ int cnt[BROWS];
    __shared__ int coff[BROWS];
    int b = blockIdx.x;
    int s = bstart[b], e = bstart[b + 1];
    int sz = e - s;
    int tid = threadIdx.x;
    if (tid < BROWS) cnt[tid] = 0;
    __syncthreads();
    for (int i = tid; i < sz; i += 256) {
        int2 ed = packed[s + i];
        ebuf[i] = ed;
        atomicAdd(&cnt[(ed.x >> 18) & (BROWS - 1)], 1);
    }
    __syncthreads();
    int v = (tid < BROWS) ? cnt[tid] : 0;
    if (tid < BROWS) coff[tid] = v;
    __syncthreads();
    for (int off = 1; off < BROWS; off <<= 1) {
        int add = (tid < BROWS && tid >= off) ? coff[tid - off] : 0;
        __syncthreads();
        if (tid < BROWS) coff[tid] += add;
        __syncthreads();
    }
    if (tid < BROWS) {
        int ex = coff[tid] - v;
        cnt[tid] = ex;                       // becomes the fill cursor
        int row = (b << BSHIFT) + tid;
        if (row < n_rows) offs[row] = s + ex;
    }
    if (b == nbuck - 1 && tid == 0) offs[n_rows] = e;
    __syncthreads();
    for (int i = tid; i < sz; i += 256) {
        int2 ed = ebuf[i];
        int rl = (ed.x >> 18) & (BROWS - 1);
        int pos = atomicAdd(&cnt[rl], 1);
        packed[s + pos] = make_int2(ed.x & 0x3FFFF, ed.y);   // strip tag
    }
}

// ---- cast fp32 user||item embeddings into one concatenated fp16 buffer ----
__global__ __launch_bounds__(256) void cast_concat_half(
        const float* __restrict__ a, const float* __restrict__ b,
        int na4, int ntot4, __half* __restrict__ o) {
    int stride = gridDim.x * blockDim.x;
    for (int i = blockIdx.x * blockDim.x + threadIdx.x; i < ntot4; i += stride) {
        float4 v = (i < na4) ? ((const float4*)a)[i] : ((const float4*)b)[i - na4];
        __half2 h0 = __floats2half2_rn(v.x, v.y);
        __half2 h1 = __floats2half2_rn(v.z, v.w);
        uint2 w;
        w.x = *(unsigned*)&h0;
        w.y = *(unsigned*)&h1;
        ((uint2*)o)[i] = w;
    }
}

// ---- SpMM: one wave (64 lanes == EMB) per row; fp16 gather, fp32 accum ----
// mode 0: out = acc;  yh = acc   (layer 0)
// mode 1: out += acc; yh = acc   (layer 1)
// mode 2: out = (out+acc)/3      (layer 2, no y write)
__global__ __launch_bounds__(256) void spmm_row_h(
        const int* __restrict__ offs, const int2* __restrict__ packed,
        const __half* __restrict__ xh,
        __half* __restrict__ yh, float* __restrict__ out, int n_rows, int mode) {
    int wid = (blockIdx.x * blockDim.x + threadIdx.x) >> 6;
    if (wid >= n_rows) return;
    int lane = threadIdx.x & 63;
    int r = __builtin_amdgcn_readfirstlane(wid);   // wave-uniform -> scalar path
    int s = offs[r];
    int e = offs[r + 1];
    const unsigned long long* pk = (const unsigned long long*)packed;
    float a0 = 0.f, a1 = 0.f, a2 = 0.f, a3 = 0.f;
    int k = s;
    for (; k + 3 < e; k += 4) {
        unsigned long long w0 = __builtin_nontemporal_load(pk + k);
        unsigned long long w1 = __builtin_nontemporal_load(pk + k + 1);
        unsigned long long w2 = __builtin_nontemporal_load(pk + k + 2);
        unsigned long long w3 = __builtin_nontemporal_load(pk + k + 3);
        int c0 = (int)(unsigned)w0;
        int c1 = (int)(unsigned)w1;
        int c2 = (int)(unsigned)w2;
        int c3 = (int)(unsigned)w3;
        float h0 = __half2float(xh[(c0 << 6) + lane]);
        float h1 = __half2float(xh[(c1 << 6) + lane]);
        float h2 = __half2float(xh[(c2 << 6) + lane]);
        float h3 = __half2float(xh[(c3 << 6) + lane]);
        a0 += __int_as_float((int)(w0 >> 32)) * h0;
        a1 += __int_as_float((int)(w1 >> 32)) * h1;
        a2 += __int_as_float((int)(w2 >> 32)) * h2;
        a3 += __int_as_float((int)(w3 >> 32)) * h3;
    }
    for (; k < e; ++k) {
        unsigned long long w = __builtin_nontemporal_load(pk + k);
        a0 += __int_as_float((int)(w >> 32)) *
              __half2float(xh[(((int)(unsigned)w) << 6) + lane]);
    }
    float acc = (a0 + a1) + (a2 + a3);
    size_t oi = ((size_t)r << 6) + lane;
    if (mode == 0) {
        __builtin_nontemporal_store(acc, &out[oi]);
        yh[oi] = __float2half_rn(acc);
    } else if (mode == 1) {
        float o = __builtin_nontemporal_load(&out[oi]);
        __builtin_nontemporal_store(o + acc, &out[oi]);
        yh[oi] = __float2half_rn(acc);
    } else {
        float o = __builtin_nontemporal_load(&out[oi]);
        __builtin_nontemporal_store((o + acc) * (1.0f / 3.0f), &out[oi]);
    }
}

extern "C" void kernel_launch(void* const* d_in, const int* in_sizes, int n_in,
                              void* d_out, int out_size, void* d_ws, size_t ws_size,
                              hipStream_t stream) {
    const float* user_emb = (const float*)d_in[0];
    const float* item_emb = (const float*)d_in[1];
    const int*   adj_row  = (const int*)d_in[2];
    const int*   adj_col  = (const int*)d_in[3];
    const float* adj_val  = (const float*)d_in[4];
    float* out = (float*)d_out;

    const int n_user = in_sizes[0] / EMB;
    const int n_item = in_sizes[1] / EMB;
    const int n      = n_user + n_item;
    const int nnz    = in_sizes[2];
    const size_t half_bytes = (size_t)n * EMB * sizeof(__half);
    const int nbuck  = (n + BROWS - 1) >> BSHIFT;

    char* p = (char*)d_ws;
    __half* X0    = (__half*)p; p += half_bytes;
    __half* Ah    = (__half*)p; p += half_bytes;
    __half* Bh    = (__half*)p; p += half_bytes;
    int2*  packed = (int2*)p;  p += (size_t)nnz * sizeof(int2);
    int*   offs   = (int*)p;   p += (size_t)(n + 1) * sizeof(int);
    int*   bstart = (int*)p;   p += (size_t)(nbuck + 1) * sizeof(int);
    int*   cursor = (int*)p;   p += (size_t)nbuck * sizeof(int);
    int*   counts = (int*)p;   p += (size_t)nbuck * sizeof(int);

    // ---- fp16 cast of the layer-0 input (single concat buffer) ----
    cast_concat_half<<<2048, 256, 0, stream>>>(user_emb, item_emb,
                                               n_user * EMB / 4, n * EMB / 4, X0);

    // ---- build bucketed edge list, then exact CSR via per-bucket sort ----
    hipMemsetAsync(counts, 0, (size_t)nbuck * sizeof(int), stream);
    bucket_hist<<<256, 256, 0, stream>>>(adj_row, counts, nnz, nbuck);
    scan_buckets<<<1, 256, 0, stream>>>(counts, bstart, cursor, nbuck);
    bucket_scatter<<<(nnz + CHUNK - 1) / CHUNK, 256, 0, stream>>>(
        adj_row, adj_col, adj_val, cursor, packed, nnz);
    sort_bucket<<<nbuck, 256, 0, stream>>>(packed, bstart, offs, n, nbuck);

    // ---- 3 propagation layers, fused accumulate ----
    const int sgrid = (n * EMB + 255) / 256;   // one wave per row
    spmm_row_h<<<sgrid, 256, 0, stream>>>(offs, packed, X0, Ah, out, n, 0);
    spmm_row_h<<<sgrid, 256, 0, stream>>>(offs, packed, Ah, Bh, out, n, 1);
    spmm_row_h<<<sgrid, 256, 0, stream>>>(offs, packed, Bh, Bh, out, n, 2);
}